// Round 3
// baseline (318.728 us; speedup 1.0000x reference)
//
#include <hip/hip_runtime.h>
#include <stdint.h>

#define B_ 2
#define T_ 4096
#define D_ 768
#define H_ 12
#define DK_ 64
#define BH_ 24

typedef unsigned short u16;
typedef unsigned int u32;
typedef __bf16 bf16x8 __attribute__((ext_vector_type(8)));
typedef float f32x4 __attribute__((ext_vector_type(4)));
typedef short s16x8 __attribute__((ext_vector_type(8)));

__device__ __forceinline__ float exp2_raw(float x) {
#if __has_builtin(__builtin_amdgcn_exp2f)
    return __builtin_amdgcn_exp2f(x);
#else
    float y; asm("v_exp_f32 %0, %1" : "=v"(y) : "v"(x)); return y;
#endif
}

__device__ __forceinline__ f32x4 mfma16(bf16x8 a, bf16x8 b, f32x4 c) {
    return __builtin_amdgcn_mfma_f32_16x16x32_bf16(a, b, c, 0, 0, 0);
}

__device__ __forceinline__ u16 f2bf(float f) {
    union { float f; u32 u; } v; v.f = f;
    u32 r = v.u + 0x7FFFu + ((v.u >> 16) & 1u);
    return (u16)(r >> 16);
}

// pack two floats to bf16 pair (lo | hi<<16), round-half-up, via v_perm
__device__ __forceinline__ u32 pack2bf(float lo, float hi) {
    union { float f; u32 u; } a, b; a.f = lo; b.f = hi;
    return __builtin_amdgcn_perm(b.u + 0x8000u, a.u + 0x8000u, 0x07060302u);
}

// async 16B global->LDS; lds base must be wave-uniform, lane i lands at base+i*16
__device__ __forceinline__ void gll16(const u16* g, u16* l) {
    __builtin_amdgcn_global_load_lds(
        (const __attribute__((address_space(1))) u32*)g,
        (__attribute__((address_space(3))) u32*)l, 16, 0, 0);
}

// ---------------- x: fp32 -> bf16 -------------------------------------------
__global__ __launch_bounds__(256) void convert_x_kernel(
    const float* __restrict__ x, u16* __restrict__ xb)
{
    int i = (blockIdx.x * 256 + threadIdx.x) * 8;
    float4 a = *(const float4*)&x[i];
    float4 b = *(const float4*)&x[i + 4];
    uint4 dd;
    dd.x = pack2bf(a.x, a.y); dd.y = pack2bf(a.z, a.w);
    dd.z = pack2bf(b.x, b.y); dd.w = pack2bf(b.z, b.w);
    *(uint4*)&xb[i] = dd;
}

// ------- weight transpose+cast: W fp32 [in][out] -> WT bf16 [out][in] x4 ----
__global__ __launch_bounds__(256) void wtrans_kernel(
    const float* __restrict__ w0, const float* __restrict__ w1,
    const float* __restrict__ w2, const float* __restrict__ w3,
    u16* __restrict__ out)
{
    __shared__ u16 tile[32][33];
    const float* src = (blockIdx.z == 0) ? w0 : (blockIdx.z == 1) ? w1 : (blockIdx.z == 2) ? w2 : w3;
    u16* dst = out + (size_t)blockIdx.z * D_ * D_;
    int tx = threadIdx.x, ty = threadIdx.y;
    int x0 = blockIdx.x * 32, y0 = blockIdx.y * 32;
    for (int i = ty; i < 32; i += 8) tile[i][tx] = f2bf(src[(size_t)(y0 + i) * D_ + x0 + tx]);
    __syncthreads();
    for (int i = ty; i < 32; i += 8) dst[(size_t)(x0 + i) * D_ + y0 + tx] = tile[tx][i];
}

// ---------------- GEMM: C[M][N] = A[M][K] * Bt[N][K]^T, K=768 ---------------
// m97-style: global_load_lds 16B staging, unpadded LDS with XOR chunk swizzle
// LDS[row][c8] holds global chunk c8 ^ (row&7); swizzle realized on global side.
// MODE 0: A bf16 x, N=2304 fused QKV (Q scaled, K, V transposed). MODE 1: fp32 out.
template<int MODE>
__global__ __launch_bounds__(256) void gemm_bt(
    const u16* __restrict__ A, const u16* __restrict__ Bt, void* __restrict__ outv)
{
    __shared__ u16 As[128 * 64];
    __shared__ u16 Bs[128 * 64];
    const int K = 768;
    int tid = threadIdx.x;
    int lane = tid & 63, wave = tid >> 6;
    int r = lane & 15, quad = lane >> 4;
    int rx = r & 7;
    int m0 = blockIdx.y * 128, n0 = blockIdx.x * 128;
    int wrow = (wave >> 1) * 64, wcol = (wave & 1) * 64;

    // staging: lane l covers row = wave*32 + j*8 + (l>>3), global chunk (l&7)^((l>>3)&7)
    int srow = wave * 32 + (lane >> 3);
    int scol = ((lane & 7) ^ (lane >> 3)) * 8;
    const u16* Ag = A + (size_t)(m0 + srow) * K + scol;
    const u16* Bg = Bt + (size_t)(n0 + srow) * K + scol;

    f32x4 acc[4][4];
    #pragma unroll
    for (int i = 0; i < 4; i++)
        #pragma unroll
        for (int j = 0; j < 4; j++)
            #pragma unroll
            for (int e = 0; e < 4; e++) acc[i][j][e] = 0.f;

    for (int k0 = 0; k0 < K; k0 += 64) {
        __syncthreads();
        #pragma unroll
        for (int j = 0; j < 4; j++) {
            gll16(Ag + (size_t)j * 8 * K + k0, As + (wave * 32 + j * 8) * 64);
            gll16(Bg + (size_t)j * 8 * K + k0, Bs + (wave * 32 + j * 8) * 64);
        }
        __syncthreads();
        #pragma unroll
        for (int ks = 0; ks < 2; ks++) {
            int swz = ((ks * 4 + quad) ^ rx) * 8;
            bf16x8 af[4], bfr[4];
            #pragma unroll
            for (int mi = 0; mi < 4; mi++)
                af[mi] = *(const bf16x8*)&As[(wrow + mi * 16 + r) * 64 + swz];
            #pragma unroll
            for (int ni = 0; ni < 4; ni++)
                bfr[ni] = *(const bf16x8*)&Bs[(wcol + ni * 16 + r) * 64 + swz];
            #pragma unroll
            for (int mi = 0; mi < 4; mi++)
                #pragma unroll
                for (int ni = 0; ni < 4; ni++)
                    acc[mi][ni] = mfma16(af[mi], bfr[ni], acc[mi][ni]);
        }
    }

    if (MODE == 0) {
        u16* out = (u16*)outv;
        int which = n0 / D_;
        int nb = n0 % D_;
        const size_t HS = (size_t)B_ * H_ * T_ * DK_;
        if (which == 2) {
            u16* vt = out + 2 * HS;
            #pragma unroll
            for (int mi = 0; mi < 4; mi++) {
                int mg = m0 + wrow + mi * 16 + quad * 4;
                int b = mg >> 12, t = mg & 4095;
                #pragma unroll
                for (int ni = 0; ni < 4; ni++) {
                    int ng = nb + wcol + ni * 16 + r;
                    int h = ng >> 6, dk = ng & 63;
                    uint2 d;
                    d.x = pack2bf(acc[mi][ni][0], acc[mi][ni][1]);
                    d.y = pack2bf(acc[mi][ni][2], acc[mi][ni][3]);
                    *(uint2*)&vt[(((size_t)(b * H_ + h)) * DK_ + dk) * T_ + t] = d;
                }
            }
        } else {
            const float cf = (which == 0) ? 0.18033688011112042f : 1.0f; // 0.125*log2(e)
            size_t wbase = (size_t)which * HS;
            #pragma unroll
            for (int mi = 0; mi < 4; mi++) {
                #pragma unroll
                for (int ni = 0; ni < 4; ni++) {
                    int ng = nb + wcol + ni * 16 + r;
                    int h = ng >> 6, dk = ng & 63;
                    #pragma unroll
                    for (int e = 0; e < 4; e++) {
                        int mg = m0 + wrow + mi * 16 + quad * 4 + e;
                        int b = mg >> 12, t = mg & 4095;
                        out[wbase + (((size_t)(b * H_ + h)) * T_ + t) * DK_ + dk]
                            = f2bf(acc[mi][ni][e] * cf);
                    }
                }
            }
        }
    } else {
        float* out = (float*)outv;
        #pragma unroll
        for (int mi = 0; mi < 4; mi++)
            #pragma unroll
            for (int ni = 0; ni < 4; ni++)
                #pragma unroll
                for (int e = 0; e < 4; e++)
                    out[(size_t)(m0 + wrow + mi * 16 + quad * 4 + e) * D_ + n0 + wcol + ni * 16 + r]
                        = acc[mi][ni][e];
    }
}

// ---------------- flash attention: S^T, no-max, KV-split, q=64/wave ---------
// Q (pre-scaled), K: [bh][t][dk]; VT: [bh][dk][t]
// Block: 256 q (4 waves x 64), kv tile 64, kv range [z*chunk, +chunk).
// P stays IN REGISTERS: QK^T MFMA n=2s+p feeds K rows perm(i)=s*32+(i>>2)*8+p*4+(i&3),
// so each lane's C-rows (quad*4+e) land exactly on its PV B-fragment kv slots
// (kv = s*32+quad*8+j). No Pt LDS buffer, no cross-lane exchange.
// LDS chunk swizzle retuned for the permuted K reads: f(row)=((row>>3)&1)*4+(row&3)
// (2-way on both K-frag and V-frag ds_read_b128 -> free per m136).
// z-split (nz runtime, 2 or 4) raises grid to 6 blocks/CU for latency hiding.
__global__ __launch_bounds__(256, 3) void attn_kernel(
    const u16* __restrict__ Q, const u16* __restrict__ K,
    const u16* __restrict__ VT, float* __restrict__ pO, float* __restrict__ pL,
    int kvchunk)
{
    __shared__ u16 Ks[64 * 64];       // [kv][dk], chunk-swizzled
    __shared__ u16 Vs[64 * 64];       // [dk][kv], chunk-swizzled

    int tid = threadIdx.x;
    int lane = tid & 63, w = tid >> 6;
    int r = lane & 15, quad = lane >> 4;
    int bh = blockIdx.y;
    int q0 = blockIdx.x * 256;
    int z = blockIdx.z;

    bf16x8 qf[4][2];
    #pragma unroll
    for (int qi = 0; qi < 4; qi++) {
        const u16* Qb = Q + ((size_t)bh * T_ + q0 + w * 64 + qi * 16 + r) * DK_;
        qf[qi][0] = *(const bf16x8*)(Qb + quad * 8);
        qf[qi][1] = *(const bf16x8*)(Qb + 32 + quad * 8);
    }

    bf16x8 ones;
    #pragma unroll
    for (int j = 0; j < 8; j++) ones[j] = (__bf16)1.0f;

    f32x4 o[4][4];      // [qi][ndk]
    f32x4 lacc[4];
    #pragma unroll
    for (int qi = 0; qi < 4; qi++) {
        #pragma unroll
        for (int e = 0; e < 4; e++) lacc[qi][e] = 0.f;
        #pragma unroll
        for (int n = 0; n < 4; n++)
            #pragma unroll
            for (int e = 0; e < 4; e++) o[qi][n][e] = 0.f;
    }

    int kb0 = z * kvchunk, kb1 = kb0 + kvchunk;
    int rb = ((r >> 2) * 8) + (r & 3);   // base of permuted K row for this lane

    for (int kb = kb0; kb < kb1; kb += 64) {
        __syncthreads();
        #pragma unroll
        for (int i = 0; i < 2; i++) {
            int c = tid + i * 256;
            int row = c >> 3, gc = c & 7;
            int fr = ((row >> 3) & 1) * 4 + (row & 3);
            int lc = gc ^ fr;
            *(bf16x8*)&Ks[row * 64 + lc * 8] =
                *(const bf16x8*)&K[((size_t)bh * T_ + kb + row) * DK_ + gc * 8];
            *(bf16x8*)&Vs[row * 64 + lc * 8] =
                *(const bf16x8*)&VT[((size_t)bh * DK_ + row) * T_ + kb + gc * 8];
        }
        __syncthreads();

        #pragma unroll
        for (int s = 0; s < 2; s++) {
            // K fragments, permuted rows: p=0 -> rowA, p=1 -> rowB
            int rowA = s * 32 + rb;
            int rowB = rowA + 4;
            int fA = ((rowA >> 3) & 1) * 4 + (rowA & 3);
            int fB = ((rowB >> 3) & 1) * 4 + (rowB & 3);
            bf16x8 kA0 = *(const bf16x8*)&Ks[rowA * 64 + (quad ^ fA) * 8];
            bf16x8 kA1 = *(const bf16x8*)&Ks[rowA * 64 + (((4 + quad) ^ fA)) * 8];
            bf16x8 kB0 = *(const bf16x8*)&Ks[rowB * 64 + (quad ^ fB) * 8];
            bf16x8 kB1 = *(const bf16x8*)&Ks[rowB * 64 + (((4 + quad) ^ fB)) * 8];
            // V fragments for this kv half (global chunks s*4+quad)
            bf16x8 vf[4];
            #pragma unroll
            for (int ndk = 0; ndk < 4; ndk++) {
                int row = ndk * 16 + r;
                int fv = ((row >> 3) & 1) * 4 + (row & 3);
                vf[ndk] = *(const bf16x8*)&Vs[row * 64 + (((s * 4 + quad) ^ fv)) * 8];
            }
            #pragma unroll
            for (int qi = 0; qi < 4; qi++) {
                f32x4 zA, zB;
                #pragma unroll
                for (int e = 0; e < 4; e++) { zA[e] = 0.f; zB[e] = 0.f; }
                zA = mfma16(kA0, qf[qi][0], zA);
                zA = mfma16(kA1, qf[qi][1], zA);
                zB = mfma16(kB0, qf[qi][0], zB);
                zB = mfma16(kB1, qf[qi][1], zB);
                // P fragment: lane's 8 slots = kv s*32+quad*8+{0..7}, q col = qi*16+r
                union { uint4 u; bf16x8 v; } pu;
                pu.u.x = pack2bf(exp2_raw(zA[0]), exp2_raw(zA[1]));
                pu.u.y = pack2bf(exp2_raw(zA[2]), exp2_raw(zA[3]));
                pu.u.z = pack2bf(exp2_raw(zB[0]), exp2_raw(zB[1]));
                pu.u.w = pack2bf(exp2_raw(zB[2]), exp2_raw(zB[3]));
                bf16x8 pf = pu.v;
                lacc[qi] = mfma16(ones, pf, lacc[qi]);
                #pragma unroll
                for (int ndk = 0; ndk < 4; ndk++)
                    o[qi][ndk] = mfma16(vf[ndk], pf, o[qi][ndk]);
            }
        }
    }

    // partial epilogue: pO[z][bh][q][dk] fp32, pL[z][bh][q]
    const size_t SP = (size_t)BH_ * T_ * DK_;
    #pragma unroll
    for (int qi = 0; qi < 4; qi++) {
        int q = q0 + w * 64 + qi * 16 + r;
        float* base = pO + (size_t)z * SP + ((size_t)bh * T_ + q) * DK_;
        #pragma unroll
        for (int ndk = 0; ndk < 4; ndk++)
            *(f32x4*)&base[ndk * 16 + quad * 4] = o[qi][ndk];
    }
    if (quad == 0) {
        #pragma unroll
        for (int qi = 0; qi < 4; qi++)
            pL[(size_t)z * BH_ * T_ + (size_t)bh * T_ + q0 + w * 64 + qi * 16 + r]
                = lacc[qi][0];
    }
}

// ---------------- combine: AO = (sum_z Oz)/(sum_z lz), bf16 -----------------
__global__ __launch_bounds__(256) void combine_kernel(
    const float* __restrict__ pO, const float* __restrict__ pL, u16* __restrict__ AO,
    int nz)
{
    const size_t SP = (size_t)BH_ * T_ * DK_;
    const size_t LP = (size_t)BH_ * T_;
    int bh = blockIdx.y;
    int b = bh / H_, h = bh % H_;
    int q = blockIdx.x * 64 + (threadIdx.x >> 2);
    int dk0 = (threadIdx.x & 3) * 16;
    size_t idx = ((size_t)bh * T_ + q) * DK_ + dk0;
    float l = 0.f;
    for (int z = 0; z < nz; z++) l += pL[(size_t)z * LP + (size_t)bh * T_ + q];
    float inv = 1.0f / l;
    u16* dst = AO + ((size_t)b * T_ + q) * D_ + h * DK_ + dk0;
    #pragma unroll
    for (int i = 0; i < 2; i++) {
        float4 s0, s1;
        s0.x = s0.y = s0.z = s0.w = 0.f;
        s1.x = s1.y = s1.z = s1.w = 0.f;
        for (int z = 0; z < nz; z++) {
            float4 a0 = *(const float4*)&pO[(size_t)z * SP + idx + i * 8];
            float4 a1 = *(const float4*)&pO[(size_t)z * SP + idx + i * 8 + 4];
            s0.x += a0.x; s0.y += a0.y; s0.z += a0.z; s0.w += a0.w;
            s1.x += a1.x; s1.y += a1.y; s1.z += a1.z; s1.w += a1.w;
        }
        uint4 dd;
        dd.x = pack2bf(s0.x * inv, s0.y * inv);
        dd.y = pack2bf(s0.z * inv, s0.w * inv);
        dd.z = pack2bf(s1.x * inv, s1.y * inv);
        dd.w = pack2bf(s1.z * inv, s1.w * inv);
        *(uint4*)&dst[i * 8] = dd;
    }
}

// ---------------- launch -----------------------------------------------------
extern "C" void kernel_launch(void* const* d_in, const int* in_sizes, int n_in,
                              void* d_out, int out_size, void* d_ws, size_t ws_size,
                              hipStream_t stream)
{
    const float* x  = (const float*)d_in[0];
    const float* wq = (const float*)d_in[1];
    const float* wk = (const float*)d_in[2];
    const float* wv = (const float*)d_in[3];
    const float* wp = (const float*)d_in[4];

    u16* ws = (u16*)d_ws;
    const size_t XS = (size_t)B_ * T_ * D_;
    const size_t WT = (size_t)D_ * D_;
    const size_t HS = (size_t)B_ * H_ * T_ * DK_;
    const size_t SP = (size_t)BH_ * T_ * DK_;
    const size_t LP = (size_t)BH_ * T_;

    u16* xb = ws;                    // x as bf16
    u16* wt = xb + XS;               // 4 transposed weights
    u16* q  = wt + 4 * WT;           // Q, K, VT each HS
    u16* k  = q + HS;
    u16* vt = k + HS;
    u16* ao = vt + HS;               // attention out bf16 [B*T][D]
    float* pL = (float*)(ao + HS);   // nz * BH * T floats

    // pick nz=4 (6 blocks/CU in attn) if workspace allows, else nz=2
    size_t fixed_bytes = (XS + 4 * WT + 4 * HS) * sizeof(u16);
    size_t need4 = fixed_bytes + (4 * LP + 4 * SP) * sizeof(float);
    int nz = (ws_size >= need4) ? 4 : 2;
    float* pO = pL + (size_t)nz * LP;

    convert_x_kernel<<<dim3(3072), 256, 0, stream>>>(x, xb);
    wtrans_kernel<<<dim3(24, 24, 4), dim3(32, 8), 0, stream>>>(wq, wk, wv, wp, wt);
    gemm_bt<0><<<dim3(18, 64), 256, 0, stream>>>(xb, wt, q);
    attn_kernel<<<dim3(16, 24, nz), 256, 0, stream>>>(q, k, vt, pO, pL, T_ / nz);
    combine_kernel<<<dim3(64, 24), 256, 0, stream>>>(pO, pL, ao, nz);
    gemm_bt<1><<<dim3(6, 64), 256, 0, stream>>>(ao, wt + 3 * WT, d_out);
}

// Round 4
// 316.084 us; speedup vs baseline: 1.0084x; 1.0084x over previous
//
#include <hip/hip_runtime.h>
#include <stdint.h>

#define B_ 2
#define T_ 4096
#define D_ 768
#define H_ 12
#define DK_ 64
#define BH_ 24

typedef unsigned short u16;
typedef unsigned int u32;
typedef __bf16 bf16x8 __attribute__((ext_vector_type(8)));
typedef float f32x4 __attribute__((ext_vector_type(4)));
typedef short s16x8 __attribute__((ext_vector_type(8)));

__device__ __forceinline__ float exp2_raw(float x) {
#if __has_builtin(__builtin_amdgcn_exp2f)
    return __builtin_amdgcn_exp2f(x);
#else
    float y; asm("v_exp_f32 %0, %1" : "=v"(y) : "v"(x)); return y;
#endif
}

__device__ __forceinline__ f32x4 mfma16(bf16x8 a, bf16x8 b, f32x4 c) {
    return __builtin_amdgcn_mfma_f32_16x16x32_bf16(a, b, c, 0, 0, 0);
}

__device__ __forceinline__ u16 f2bf(float f) {
    union { float f; u32 u; } v; v.f = f;
    u32 r = v.u + 0x7FFFu + ((v.u >> 16) & 1u);
    return (u16)(r >> 16);
}

// pack two floats to bf16 pair (lo | hi<<16), round-half-up, via v_perm
__device__ __forceinline__ u32 pack2bf(float lo, float hi) {
    union { float f; u32 u; } a, b; a.f = lo; b.f = hi;
    return __builtin_amdgcn_perm(b.u + 0x8000u, a.u + 0x8000u, 0x07060302u);
}

// async 16B global->LDS; lds base must be wave-uniform, lane i lands at base+i*16
__device__ __forceinline__ void gll16(const u16* g, u16* l) {
    __builtin_amdgcn_global_load_lds(
        (const __attribute__((address_space(1))) u32*)g,
        (__attribute__((address_space(3))) u32*)l, 16, 0, 0);
}

// ---------------- x: fp32 -> bf16 -------------------------------------------
__global__ __launch_bounds__(256) void convert_x_kernel(
    const float* __restrict__ x, u16* __restrict__ xb)
{
    int i = (blockIdx.x * 256 + threadIdx.x) * 8;
    float4 a = *(const float4*)&x[i];
    float4 b = *(const float4*)&x[i + 4];
    uint4 dd;
    dd.x = pack2bf(a.x, a.y); dd.y = pack2bf(a.z, a.w);
    dd.z = pack2bf(b.x, b.y); dd.w = pack2bf(b.z, b.w);
    *(uint4*)&xb[i] = dd;
}

// ------- weight transpose+cast: W fp32 [in][out] -> WT bf16 [out][in] x4 ----
__global__ __launch_bounds__(256) void wtrans_kernel(
    const float* __restrict__ w0, const float* __restrict__ w1,
    const float* __restrict__ w2, const float* __restrict__ w3,
    u16* __restrict__ out)
{
    __shared__ u16 tile[32][33];
    const float* src = (blockIdx.z == 0) ? w0 : (blockIdx.z == 1) ? w1 : (blockIdx.z == 2) ? w2 : w3;
    u16* dst = out + (size_t)blockIdx.z * D_ * D_;
    int tx = threadIdx.x, ty = threadIdx.y;
    int x0 = blockIdx.x * 32, y0 = blockIdx.y * 32;
    for (int i = ty; i < 32; i += 8) tile[i][tx] = f2bf(src[(size_t)(y0 + i) * D_ + x0 + tx]);
    __syncthreads();
    for (int i = ty; i < 32; i += 8) dst[(size_t)(x0 + i) * D_ + y0 + tx] = tile[tx][i];
}

// ---------------- GEMM: C[M][N] = A[M][K] * Bt[N][K]^T, K=768 ---------------
// m97-style: global_load_lds 16B staging, unpadded LDS with XOR chunk swizzle
// LDS[row][c8] holds global chunk c8 ^ (row&7); swizzle realized on global side.
// MODE 0: A bf16 x, N=2304 fused QKV (Q scaled, K, V transposed). MODE 1: fp32 out.
template<int MODE>
__global__ __launch_bounds__(256) void gemm_bt(
    const u16* __restrict__ A, const u16* __restrict__ Bt, void* __restrict__ outv)
{
    __shared__ u16 As[128 * 64];
    __shared__ u16 Bs[128 * 64];
    const int K = 768;
    int tid = threadIdx.x;
    int lane = tid & 63, wave = tid >> 6;
    int r = lane & 15, quad = lane >> 4;
    int rx = r & 7;
    int m0 = blockIdx.y * 128, n0 = blockIdx.x * 128;
    int wrow = (wave >> 1) * 64, wcol = (wave & 1) * 64;

    // staging: lane l covers row = wave*32 + j*8 + (l>>3), global chunk (l&7)^((l>>3)&7)
    int srow = wave * 32 + (lane >> 3);
    int scol = ((lane & 7) ^ (lane >> 3)) * 8;
    const u16* Ag = A + (size_t)(m0 + srow) * K + scol;
    const u16* Bg = Bt + (size_t)(n0 + srow) * K + scol;

    f32x4 acc[4][4];
    #pragma unroll
    for (int i = 0; i < 4; i++)
        #pragma unroll
        for (int j = 0; j < 4; j++)
            #pragma unroll
            for (int e = 0; e < 4; e++) acc[i][j][e] = 0.f;

    for (int k0 = 0; k0 < K; k0 += 64) {
        __syncthreads();
        #pragma unroll
        for (int j = 0; j < 4; j++) {
            gll16(Ag + (size_t)j * 8 * K + k0, As + (wave * 32 + j * 8) * 64);
            gll16(Bg + (size_t)j * 8 * K + k0, Bs + (wave * 32 + j * 8) * 64);
        }
        __syncthreads();
        #pragma unroll
        for (int ks = 0; ks < 2; ks++) {
            int swz = ((ks * 4 + quad) ^ rx) * 8;
            bf16x8 af[4], bfr[4];
            #pragma unroll
            for (int mi = 0; mi < 4; mi++)
                af[mi] = *(const bf16x8*)&As[(wrow + mi * 16 + r) * 64 + swz];
            #pragma unroll
            for (int ni = 0; ni < 4; ni++)
                bfr[ni] = *(const bf16x8*)&Bs[(wcol + ni * 16 + r) * 64 + swz];
            #pragma unroll
            for (int mi = 0; mi < 4; mi++)
                #pragma unroll
                for (int ni = 0; ni < 4; ni++)
                    acc[mi][ni] = mfma16(af[mi], bfr[ni], acc[mi][ni]);
        }
    }

    if (MODE == 0) {
        u16* out = (u16*)outv;
        int which = n0 / D_;
        int nb = n0 % D_;
        const size_t HS = (size_t)B_ * H_ * T_ * DK_;
        if (which == 2) {
            u16* vt = out + 2 * HS;
            #pragma unroll
            for (int mi = 0; mi < 4; mi++) {
                int mg = m0 + wrow + mi * 16 + quad * 4;
                int b = mg >> 12, t = mg & 4095;
                #pragma unroll
                for (int ni = 0; ni < 4; ni++) {
                    int ng = nb + wcol + ni * 16 + r;
                    int h = ng >> 6, dk = ng & 63;
                    uint2 d;
                    d.x = pack2bf(acc[mi][ni][0], acc[mi][ni][1]);
                    d.y = pack2bf(acc[mi][ni][2], acc[mi][ni][3]);
                    *(uint2*)&vt[(((size_t)(b * H_ + h)) * DK_ + dk) * T_ + t] = d;
                }
            }
        } else {
            const float cf = (which == 0) ? 0.18033688011112042f : 1.0f; // 0.125*log2(e)
            size_t wbase = (size_t)which * HS;
            #pragma unroll
            for (int mi = 0; mi < 4; mi++) {
                #pragma unroll
                for (int ni = 0; ni < 4; ni++) {
                    int ng = nb + wcol + ni * 16 + r;
                    int h = ng >> 6, dk = ng & 63;
                    #pragma unroll
                    for (int e = 0; e < 4; e++) {
                        int mg = m0 + wrow + mi * 16 + quad * 4 + e;
                        int b = mg >> 12, t = mg & 4095;
                        out[wbase + (((size_t)(b * H_ + h)) * T_ + t) * DK_ + dk]
                            = f2bf(acc[mi][ni][e] * cf);
                    }
                }
            }
        }
    } else {
        float* out = (float*)outv;
        #pragma unroll
        for (int mi = 0; mi < 4; mi++)
            #pragma unroll
            for (int ni = 0; ni < 4; ni++)
                #pragma unroll
                for (int e = 0; e < 4; e++)
                    out[(size_t)(m0 + wrow + mi * 16 + quad * 4 + e) * D_ + n0 + wcol + ni * 16 + r]
                        = acc[mi][ni][e];
    }
}

// ---------------- flash attention: S^T, no-max, KV-split, q=64/wave ---------
// Q (pre-scaled), K: [bh][t][dk]; VT: [bh][dk][t]
// Block: 256 q (4 waves x 64), kv tile 64, kv range [z*chunk, +chunk).
// P stays IN REGISTERS: QK^T MFMA n=2s+p feeds K rows perm(i)=s*32+(i>>2)*8+p*4+(i&3),
// so each lane's C-rows (quad*4+e) land exactly on its PV B-fragment kv slots
// (kv = s*32+quad*8+j). No Pt LDS buffer, no cross-lane exchange.
// LDS chunk swizzle f(row)=((row>>3)&1)*4+(row&3), realized on the GLOBAL side:
// staging uses global_load_lds (zero staging VGPRs) with per-lane inverse-swizzled
// global addresses + linear LDS dest (rule #21); read side XORs f(row).
// Double-buffered LDS + stage(t+1)-before-compute(t): the vmcnt(0) drain inside
// __syncthreads only waits on loads issued a full compute phase earlier.
__global__ __launch_bounds__(256, 3) void attn_kernel(
    const u16* __restrict__ Q, const u16* __restrict__ K,
    const u16* __restrict__ VT, float* __restrict__ pO, float* __restrict__ pL,
    int kvchunk)
{
    __shared__ u16 Ks[2][64 * 64];    // [buf][kv][dk], chunk-swizzled
    __shared__ u16 Vs[2][64 * 64];    // [buf][dk][kv], chunk-swizzled

    int tid = threadIdx.x;
    int lane = tid & 63, w = tid >> 6;
    int r = lane & 15, quad = lane >> 4;
    int bh = blockIdx.y;
    int q0 = blockIdx.x * 256;
    int z = blockIdx.z;

    bf16x8 qf[4][2];
    #pragma unroll
    for (int qi = 0; qi < 4; qi++) {
        const u16* Qb = Q + ((size_t)bh * T_ + q0 + w * 64 + qi * 16 + r) * DK_;
        qf[qi][0] = *(const bf16x8*)(Qb + quad * 8);
        qf[qi][1] = *(const bf16x8*)(Qb + 32 + quad * 8);
    }

    bf16x8 ones;
    #pragma unroll
    for (int j = 0; j < 8; j++) ones[j] = (__bf16)1.0f;

    f32x4 o[4][4];      // [qi][ndk]
    f32x4 lacc[4];
    #pragma unroll
    for (int qi = 0; qi < 4; qi++) {
        #pragma unroll
        for (int e = 0; e < 4; e++) lacc[qi][e] = 0.f;
        #pragma unroll
        for (int n = 0; n < 4; n++)
            #pragma unroll
            for (int e = 0; e < 4; e++) o[qi][n][e] = 0.f;
    }

    int kb0 = z * kvchunk, kb1 = kb0 + kvchunk;
    int rb = ((r >> 2) * 8) + (r & 3);   // base of permuted K row for this lane

    // staging coords: wave w covers rows w*16 + j*8 + (lane>>3), j=0,1.
    // global chunk = (lane&7) ^ f(row); LDS dest linear (lane*16B).
    int row0 = w * 16 + (lane >> 3);
    int row1 = row0 + 8;
    int f0 = ((row0 >> 3) & 1) * 4 + (row0 & 3);
    int f1 = f0 ^ 4;
    int gc0 = (lane & 7) ^ f0;
    int gc1 = (lane & 7) ^ f1;
    const u16* Kg0 = K + ((size_t)bh * T_ + row0) * DK_ + gc0 * 8;
    const u16* Kg1 = K + ((size_t)bh * T_ + row1) * DK_ + gc1 * 8;
    const u16* Vg0 = VT + ((size_t)bh * DK_ + row0) * T_ + gc0 * 8;
    const u16* Vg1 = VT + ((size_t)bh * DK_ + row1) * T_ + gc1 * 8;

    // prologue: stage tile kb0 into buf 0
    gll16(Kg0 + (size_t)kb0 * DK_, &Ks[0][(w * 16) * 64]);
    gll16(Kg1 + (size_t)kb0 * DK_, &Ks[0][(w * 16 + 8) * 64]);
    gll16(Vg0 + kb0, &Vs[0][(w * 16) * 64]);
    gll16(Vg1 + kb0, &Vs[0][(w * 16 + 8) * 64]);
    __syncthreads();

    int cur = 0;
    for (int kb = kb0; kb < kb1; kb += 64) {
        // async stage of tile kb+64 into the other buffer (0 VGPRs, no wait here)
        if (kb + 64 < kb1) {
            int nxt = cur ^ 1;
            gll16(Kg0 + (size_t)(kb + 64) * DK_, &Ks[nxt][(w * 16) * 64]);
            gll16(Kg1 + (size_t)(kb + 64) * DK_, &Ks[nxt][(w * 16 + 8) * 64]);
            gll16(Vg0 + (kb + 64), &Vs[nxt][(w * 16) * 64]);
            gll16(Vg1 + (kb + 64), &Vs[nxt][(w * 16 + 8) * 64]);
        }
        const u16* Kc = Ks[cur];
        const u16* Vc = Vs[cur];

        #pragma unroll
        for (int s = 0; s < 2; s++) {
            // K fragments, permuted rows: p=0 -> rowA, p=1 -> rowB
            int rowA = s * 32 + rb;
            int rowB = rowA + 4;
            int fA = ((rowA >> 3) & 1) * 4 + (rowA & 3);
            int fB = ((rowB >> 3) & 1) * 4 + (rowB & 3);
            bf16x8 kA0 = *(const bf16x8*)&Kc[rowA * 64 + (quad ^ fA) * 8];
            bf16x8 kA1 = *(const bf16x8*)&Kc[rowA * 64 + (((4 + quad) ^ fA)) * 8];
            bf16x8 kB0 = *(const bf16x8*)&Kc[rowB * 64 + (quad ^ fB) * 8];
            bf16x8 kB1 = *(const bf16x8*)&Kc[rowB * 64 + (((4 + quad) ^ fB)) * 8];
            // V fragments for this kv half (global chunks s*4+quad)
            bf16x8 vf[4];
            #pragma unroll
            for (int ndk = 0; ndk < 4; ndk++) {
                int row = ndk * 16 + r;
                int fv = ((row >> 3) & 1) * 4 + (row & 3);
                vf[ndk] = *(const bf16x8*)&Vc[row * 64 + (((s * 4 + quad) ^ fv)) * 8];
            }
            #pragma unroll
            for (int qi = 0; qi < 4; qi++) {
                f32x4 zA, zB;
                #pragma unroll
                for (int e = 0; e < 4; e++) { zA[e] = 0.f; zB[e] = 0.f; }
                zA = mfma16(kA0, qf[qi][0], zA);
                zA = mfma16(kA1, qf[qi][1], zA);
                zB = mfma16(kB0, qf[qi][0], zB);
                zB = mfma16(kB1, qf[qi][1], zB);
                // P fragment: lane's 8 slots = kv s*32+quad*8+{0..7}, q col = qi*16+r
                union { uint4 u; bf16x8 v; } pu;
                pu.u.x = pack2bf(exp2_raw(zA[0]), exp2_raw(zA[1]));
                pu.u.y = pack2bf(exp2_raw(zA[2]), exp2_raw(zA[3]));
                pu.u.z = pack2bf(exp2_raw(zB[0]), exp2_raw(zB[1]));
                pu.u.w = pack2bf(exp2_raw(zB[2]), exp2_raw(zB[3]));
                bf16x8 pf = pu.v;
                lacc[qi] = mfma16(ones, pf, lacc[qi]);
                #pragma unroll
                for (int ndk = 0; ndk < 4; ndk++)
                    o[qi][ndk] = mfma16(vf[ndk], pf, o[qi][ndk]);
            }
        }
        __syncthreads();
        cur ^= 1;
    }

    // partial epilogue: pO[z][bh][q][dk] fp32, pL[z][bh][q]
    const size_t SP = (size_t)BH_ * T_ * DK_;
    #pragma unroll
    for (int qi = 0; qi < 4; qi++) {
        int q = q0 + w * 64 + qi * 16 + r;
        float* base = pO + (size_t)z * SP + ((size_t)bh * T_ + q) * DK_;
        #pragma unroll
        for (int ndk = 0; ndk < 4; ndk++)
            *(f32x4*)&base[ndk * 16 + quad * 4] = o[qi][ndk];
    }
    if (quad == 0) {
        #pragma unroll
        for (int qi = 0; qi < 4; qi++)
            pL[(size_t)z * BH_ * T_ + (size_t)bh * T_ + q0 + w * 64 + qi * 16 + r]
                = lacc[qi][0];
    }
}

// ---------------- combine: AO = (sum_z Oz)/(sum_z lz), bf16 -----------------
__global__ __launch_bounds__(256) void combine_kernel(
    const float* __restrict__ pO, const float* __restrict__ pL, u16* __restrict__ AO,
    int nz)
{
    const size_t SP = (size_t)BH_ * T_ * DK_;
    const size_t LP = (size_t)BH_ * T_;
    int bh = blockIdx.y;
    int b = bh / H_, h = bh % H_;
    int q = blockIdx.x * 64 + (threadIdx.x >> 2);
    int dk0 = (threadIdx.x & 3) * 16;
    size_t idx = ((size_t)bh * T_ + q) * DK_ + dk0;
    float l = 0.f;
    for (int z = 0; z < nz; z++) l += pL[(size_t)z * LP + (size_t)bh * T_ + q];
    float inv = 1.0f / l;
    u16* dst = AO + ((size_t)b * T_ + q) * D_ + h * DK_ + dk0;
    #pragma unroll
    for (int i = 0; i < 2; i++) {
        float4 s0, s1;
        s0.x = s0.y = s0.z = s0.w = 0.f;
        s1.x = s1.y = s1.z = s1.w = 0.f;
        for (int z = 0; z < nz; z++) {
            float4 a0 = *(const float4*)&pO[(size_t)z * SP + idx + i * 8];
            float4 a1 = *(const float4*)&pO[(size_t)z * SP + idx + i * 8 + 4];
            s0.x += a0.x; s0.y += a0.y; s0.z += a0.z; s0.w += a0.w;
            s1.x += a1.x; s1.y += a1.y; s1.z += a1.z; s1.w += a1.w;
        }
        uint4 dd;
        dd.x = pack2bf(s0.x * inv, s0.y * inv);
        dd.y = pack2bf(s0.z * inv, s0.w * inv);
        dd.z = pack2bf(s1.x * inv, s1.y * inv);
        dd.w = pack2bf(s1.z * inv, s1.w * inv);
        *(uint4*)&dst[i * 8] = dd;
    }
}

// ---------------- launch -----------------------------------------------------
extern "C" void kernel_launch(void* const* d_in, const int* in_sizes, int n_in,
                              void* d_out, int out_size, void* d_ws, size_t ws_size,
                              hipStream_t stream)
{
    const float* x  = (const float*)d_in[0];
    const float* wq = (const float*)d_in[1];
    const float* wk = (const float*)d_in[2];
    const float* wv = (const float*)d_in[3];
    const float* wp = (const float*)d_in[4];

    u16* ws = (u16*)d_ws;
    const size_t XS = (size_t)B_ * T_ * D_;
    const size_t WT = (size_t)D_ * D_;
    const size_t HS = (size_t)B_ * H_ * T_ * DK_;
    const size_t LP = (size_t)BH_ * T_;

    u16* xb = ws;                    // x as bf16
    u16* wt = xb + XS;               // 4 transposed weights
    u16* q  = wt + 4 * WT;           // Q, K, VT each HS
    u16* k  = q + HS;
    u16* vt = k + HS;
    u16* ao = vt + HS;               // attention out bf16 [B*T][D]
    float* pL = (float*)(ao + HS);   // 2 * BH * T floats
    float* pO = pL + 2 * LP;         // 2 * BH * T * DK floats

    const int nz = 2;                // register-capped occupancy: more z only adds traffic (R3)

    convert_x_kernel<<<dim3(3072), 256, 0, stream>>>(x, xb);
    wtrans_kernel<<<dim3(24, 24, 4), dim3(32, 8), 0, stream>>>(wq, wk, wv, wp, wt);
    gemm_bt<0><<<dim3(18, 64), 256, 0, stream>>>(xb, wt, q);
    attn_kernel<<<dim3(16, 24, nz), 256, 0, stream>>>(q, k, vt, pO, pL, T_ / nz);
    combine_kernel<<<dim3(64, 24), 256, 0, stream>>>(pO, pL, ao, nz);
    gemm_bt<1><<<dim3(6, 64), 256, 0, stream>>>(ao, wt + 3 * WT, d_out);
}

// Round 5
// 276.987 us; speedup vs baseline: 1.1507x; 1.1412x over previous
//
#include <hip/hip_runtime.h>
#include <stdint.h>

#define B_ 2
#define T_ 4096
#define D_ 768
#define H_ 12
#define DK_ 64
#define BH_ 24

typedef unsigned short u16;
typedef unsigned int u32;
typedef __bf16 bf16x8 __attribute__((ext_vector_type(8)));
typedef float f32x4 __attribute__((ext_vector_type(4)));
typedef short s16x8 __attribute__((ext_vector_type(8)));

__device__ __forceinline__ float exp2_raw(float x) {
#if __has_builtin(__builtin_amdgcn_exp2f)
    return __builtin_amdgcn_exp2f(x);
#else
    float y; asm("v_exp_f32 %0, %1" : "=v"(y) : "v"(x)); return y;
#endif
}

__device__ __forceinline__ f32x4 mfma16(bf16x8 a, bf16x8 b, f32x4 c) {
    return __builtin_amdgcn_mfma_f32_16x16x32_bf16(a, b, c, 0, 0, 0);
}

__device__ __forceinline__ u16 f2bf(float f) {
    union { float f; u32 u; } v; v.f = f;
    u32 r = v.u + 0x7FFFu + ((v.u >> 16) & 1u);
    return (u16)(r >> 16);
}

// pack two floats to bf16 pair (lo | hi<<16), round-half-up, via v_perm
__device__ __forceinline__ u32 pack2bf(float lo, float hi) {
    union { float f; u32 u; } a, b; a.f = lo; b.f = hi;
    return __builtin_amdgcn_perm(b.u + 0x8000u, a.u + 0x8000u, 0x07060302u);
}

// async 16B global->LDS; lds base must be wave-uniform, lane i lands at base+i*16
__device__ __forceinline__ void gll16(const u16* g, u16* l) {
    __builtin_amdgcn_global_load_lds(
        (const __attribute__((address_space(1))) u32*)g,
        (__attribute__((address_space(3))) u32*)l, 16, 0, 0);
}

// ---------------- x: fp32 -> bf16 -------------------------------------------
__global__ __launch_bounds__(256) void convert_x_kernel(
    const float* __restrict__ x, u16* __restrict__ xb)
{
    int i = (blockIdx.x * 256 + threadIdx.x) * 8;
    float4 a = *(const float4*)&x[i];
    float4 b = *(const float4*)&x[i + 4];
    uint4 dd;
    dd.x = pack2bf(a.x, a.y); dd.y = pack2bf(a.z, a.w);
    dd.z = pack2bf(b.x, b.y); dd.w = pack2bf(b.z, b.w);
    *(uint4*)&xb[i] = dd;
}

// ------- weight transpose+cast: W fp32 [in][out] -> WT bf16 [out][in] x4 ----
__global__ __launch_bounds__(256) void wtrans_kernel(
    const float* __restrict__ w0, const float* __restrict__ w1,
    const float* __restrict__ w2, const float* __restrict__ w3,
    u16* __restrict__ out)
{
    __shared__ u16 tile[32][33];
    const float* src = (blockIdx.z == 0) ? w0 : (blockIdx.z == 1) ? w1 : (blockIdx.z == 2) ? w2 : w3;
    u16* dst = out + (size_t)blockIdx.z * D_ * D_;
    int tx = threadIdx.x, ty = threadIdx.y;
    int x0 = blockIdx.x * 32, y0 = blockIdx.y * 32;
    for (int i = ty; i < 32; i += 8) tile[i][tx] = f2bf(src[(size_t)(y0 + i) * D_ + x0 + tx]);
    __syncthreads();
    for (int i = ty; i < 32; i += 8) dst[(size_t)(x0 + i) * D_ + y0 + tx] = tile[tx][i];
}

// ---------------- GEMM: C[M][N] = A[M][K] * Bt[N][K]^T, K=768 ---------------
// m97-style: global_load_lds 16B staging, unpadded LDS with XOR chunk swizzle
// LDS[row][c8] holds global chunk c8 ^ (row&7); swizzle realized on global side.
// MODE 0: A bf16 x, N=2304 fused QKV (Q scaled, K, V transposed). MODE 1: fp32 out.
template<int MODE>
__global__ __launch_bounds__(256) void gemm_bt(
    const u16* __restrict__ A, const u16* __restrict__ Bt, void* __restrict__ outv)
{
    __shared__ u16 As[128 * 64];
    __shared__ u16 Bs[128 * 64];
    const int K = 768;
    int tid = threadIdx.x;
    int lane = tid & 63, wave = tid >> 6;
    int r = lane & 15, quad = lane >> 4;
    int rx = r & 7;
    int m0 = blockIdx.y * 128, n0 = blockIdx.x * 128;
    int wrow = (wave >> 1) * 64, wcol = (wave & 1) * 64;

    // staging: lane l covers row = wave*32 + j*8 + (l>>3), global chunk (l&7)^((l>>3)&7)
    int srow = wave * 32 + (lane >> 3);
    int scol = ((lane & 7) ^ (lane >> 3)) * 8;
    const u16* Ag = A + (size_t)(m0 + srow) * K + scol;
    const u16* Bg = Bt + (size_t)(n0 + srow) * K + scol;

    f32x4 acc[4][4];
    #pragma unroll
    for (int i = 0; i < 4; i++)
        #pragma unroll
        for (int j = 0; j < 4; j++)
            #pragma unroll
            for (int e = 0; e < 4; e++) acc[i][j][e] = 0.f;

    for (int k0 = 0; k0 < K; k0 += 64) {
        __syncthreads();
        #pragma unroll
        for (int j = 0; j < 4; j++) {
            gll16(Ag + (size_t)j * 8 * K + k0, As + (wave * 32 + j * 8) * 64);
            gll16(Bg + (size_t)j * 8 * K + k0, Bs + (wave * 32 + j * 8) * 64);
        }
        __syncthreads();
        #pragma unroll
        for (int ks = 0; ks < 2; ks++) {
            int swz = ((ks * 4 + quad) ^ rx) * 8;
            bf16x8 af[4], bfr[4];
            #pragma unroll
            for (int mi = 0; mi < 4; mi++)
                af[mi] = *(const bf16x8*)&As[(wrow + mi * 16 + r) * 64 + swz];
            #pragma unroll
            for (int ni = 0; ni < 4; ni++)
                bfr[ni] = *(const bf16x8*)&Bs[(wcol + ni * 16 + r) * 64 + swz];
            #pragma unroll
            for (int mi = 0; mi < 4; mi++)
                #pragma unroll
                for (int ni = 0; ni < 4; ni++)
                    acc[mi][ni] = mfma16(af[mi], bfr[ni], acc[mi][ni]);
        }
    }

    if (MODE == 0) {
        u16* out = (u16*)outv;
        int which = n0 / D_;
        int nb = n0 % D_;
        const size_t HS = (size_t)B_ * H_ * T_ * DK_;
        if (which == 2) {
            u16* vt = out + 2 * HS;
            #pragma unroll
            for (int mi = 0; mi < 4; mi++) {
                int mg = m0 + wrow + mi * 16 + quad * 4;
                int b = mg >> 12, t = mg & 4095;
                #pragma unroll
                for (int ni = 0; ni < 4; ni++) {
                    int ng = nb + wcol + ni * 16 + r;
                    int h = ng >> 6, dk = ng & 63;
                    uint2 d;
                    d.x = pack2bf(acc[mi][ni][0], acc[mi][ni][1]);
                    d.y = pack2bf(acc[mi][ni][2], acc[mi][ni][3]);
                    *(uint2*)&vt[(((size_t)(b * H_ + h)) * DK_ + dk) * T_ + t] = d;
                }
            }
        } else {
            const float cf = (which == 0) ? 0.18033688011112042f : 1.0f; // 0.125*log2(e)
            size_t wbase = (size_t)which * HS;
            #pragma unroll
            for (int mi = 0; mi < 4; mi++) {
                #pragma unroll
                for (int ni = 0; ni < 4; ni++) {
                    int ng = nb + wcol + ni * 16 + r;
                    int h = ng >> 6, dk = ng & 63;
                    #pragma unroll
                    for (int e = 0; e < 4; e++) {
                        int mg = m0 + wrow + mi * 16 + quad * 4 + e;
                        int b = mg >> 12, t = mg & 4095;
                        out[wbase + (((size_t)(b * H_ + h)) * T_ + t) * DK_ + dk]
                            = f2bf(acc[mi][ni][e] * cf);
                    }
                }
            }
        }
    } else {
        float* out = (float*)outv;
        #pragma unroll
        for (int mi = 0; mi < 4; mi++)
            #pragma unroll
            for (int ni = 0; ni < 4; ni++)
                #pragma unroll
                for (int e = 0; e < 4; e++)
                    out[(size_t)(m0 + wrow + mi * 16 + quad * 4 + e) * D_ + n0 + wcol + ni * 16 + r]
                        = acc[mi][ni][e];
    }
}

// ---------------- flash attention: S^T, no-max, KV-split, q=64/wave ---------
// Q (pre-scaled), K: [bh][t][dk]; VT: [bh][dk][t]
// Block: 256 q (4 waves x 64), kv tile 64, kv range [z*2048, +2048).
// P stays IN REGISTERS: QK^T MFMA n=2s+p feeds K rows perm(i)=s*32+(i>>2)*8+p*4+(i&3),
// so each lane's C-rows (quad*4+e) land exactly on its PV B-fragment kv slots
// (kv = s*32+quad*8+j). No Pt LDS buffer, no cross-lane exchange.
// LDS chunk swizzle retuned for the permuted K reads: f(row)=((row>>3)&1)*4+(row&3)
// (2-way on both K-frag and V-frag ds_read_b128 -> free per m136).
// T1 XCD swizzle: flat 768-block grid; hw round-robin (xcd = wgid%8) decoded so
// each XCD owns 3 bh entirely -> K+V working set 3MB fits its 4MB L2;
// the 16 q-blocks + both z sharing a bh hit L2 instead of refetching HBM.
__global__ __launch_bounds__(256, 3) void attn_kernel(
    const u16* __restrict__ Q, const u16* __restrict__ K,
    const u16* __restrict__ VT, float* __restrict__ pO, float* __restrict__ pL)
{
    __shared__ u16 Ks[64 * 64];       // [kv][dk], chunk-swizzled
    __shared__ u16 Vs[64 * 64];       // [dk][kv], chunk-swizzled

    int tid = threadIdx.x;
    int lane = tid & 63, w = tid >> 6;
    int r = lane & 15, quad = lane >> 4;

    // XCD-aware decode of flat wgid (768 = 8 xcd * 3 bh * 2 z * 16 qblk)
    int wgid = blockIdx.x;
    int xcd = wgid & 7, slot = wgid >> 3;
    int bh = xcd * 3 + (slot >> 5);
    int rem = slot & 31;
    int z = rem >> 4;
    int q0 = (rem & 15) * 256;

    bf16x8 qf[4][2];
    #pragma unroll
    for (int qi = 0; qi < 4; qi++) {
        const u16* Qb = Q + ((size_t)bh * T_ + q0 + w * 64 + qi * 16 + r) * DK_;
        qf[qi][0] = *(const bf16x8*)(Qb + quad * 8);
        qf[qi][1] = *(const bf16x8*)(Qb + 32 + quad * 8);
    }

    bf16x8 ones;
    #pragma unroll
    for (int j = 0; j < 8; j++) ones[j] = (__bf16)1.0f;

    f32x4 o[4][4];      // [qi][ndk]
    f32x4 lacc[4];
    #pragma unroll
    for (int qi = 0; qi < 4; qi++) {
        #pragma unroll
        for (int e = 0; e < 4; e++) lacc[qi][e] = 0.f;
        #pragma unroll
        for (int n = 0; n < 4; n++)
            #pragma unroll
            for (int e = 0; e < 4; e++) o[qi][n][e] = 0.f;
    }

    int kb0 = z * (T_ / 2), kb1 = kb0 + T_ / 2;
    int rb = ((r >> 2) * 8) + (r & 3);   // base of permuted K row for this lane

    for (int kb = kb0; kb < kb1; kb += 64) {
        __syncthreads();
        #pragma unroll
        for (int i = 0; i < 2; i++) {
            int c = tid + i * 256;
            int row = c >> 3, gc = c & 7;
            int fr = ((row >> 3) & 1) * 4 + (row & 3);
            int lc = gc ^ fr;
            *(bf16x8*)&Ks[row * 64 + lc * 8] =
                *(const bf16x8*)&K[((size_t)bh * T_ + kb + row) * DK_ + gc * 8];
            *(bf16x8*)&Vs[row * 64 + lc * 8] =
                *(const bf16x8*)&VT[((size_t)bh * DK_ + row) * T_ + kb + gc * 8];
        }
        __syncthreads();

        #pragma unroll
        for (int s = 0; s < 2; s++) {
            // K fragments, permuted rows: p=0 -> rowA, p=1 -> rowB
            int rowA = s * 32 + rb;
            int rowB = rowA + 4;
            int fA = ((rowA >> 3) & 1) * 4 + (rowA & 3);
            int fB = ((rowB >> 3) & 1) * 4 + (rowB & 3);
            bf16x8 kA0 = *(const bf16x8*)&Ks[rowA * 64 + (quad ^ fA) * 8];
            bf16x8 kA1 = *(const bf16x8*)&Ks[rowA * 64 + (((4 + quad) ^ fA)) * 8];
            bf16x8 kB0 = *(const bf16x8*)&Ks[rowB * 64 + (quad ^ fB) * 8];
            bf16x8 kB1 = *(const bf16x8*)&Ks[rowB * 64 + (((4 + quad) ^ fB)) * 8];
            // V fragments for this kv half (global chunks s*4+quad)
            bf16x8 vf[4];
            #pragma unroll
            for (int ndk = 0; ndk < 4; ndk++) {
                int row = ndk * 16 + r;
                int fv = ((row >> 3) & 1) * 4 + (row & 3);
                vf[ndk] = *(const bf16x8*)&Vs[row * 64 + (((s * 4 + quad) ^ fv)) * 8];
            }
            #pragma unroll
            for (int qi = 0; qi < 4; qi++) {
                f32x4 zA, zB;
                #pragma unroll
                for (int e = 0; e < 4; e++) { zA[e] = 0.f; zB[e] = 0.f; }
                zA = mfma16(kA0, qf[qi][0], zA);
                zA = mfma16(kA1, qf[qi][1], zA);
                zB = mfma16(kB0, qf[qi][0], zB);
                zB = mfma16(kB1, qf[qi][1], zB);
                // P fragment: lane's 8 slots = kv s*32+quad*8+{0..7}, q col = qi*16+r
                union { uint4 u; bf16x8 v; } pu;
                pu.u.x = pack2bf(exp2_raw(zA[0]), exp2_raw(zA[1]));
                pu.u.y = pack2bf(exp2_raw(zA[2]), exp2_raw(zA[3]));
                pu.u.z = pack2bf(exp2_raw(zB[0]), exp2_raw(zB[1]));
                pu.u.w = pack2bf(exp2_raw(zB[2]), exp2_raw(zB[3]));
                bf16x8 pf = pu.v;
                lacc[qi] = mfma16(ones, pf, lacc[qi]);
                #pragma unroll
                for (int ndk = 0; ndk < 4; ndk++)
                    o[qi][ndk] = mfma16(vf[ndk], pf, o[qi][ndk]);
            }
        }
    }

    // partial epilogue: pO[z][bh][q][dk] fp32, pL[z][bh][q]
    const size_t SP = (size_t)BH_ * T_ * DK_;
    #pragma unroll
    for (int qi = 0; qi < 4; qi++) {
        int q = q0 + w * 64 + qi * 16 + r;
        float* base = pO + (size_t)z * SP + ((size_t)bh * T_ + q) * DK_;
        #pragma unroll
        for (int ndk = 0; ndk < 4; ndk++)
            *(f32x4*)&base[ndk * 16 + quad * 4] = o[qi][ndk];
    }
    if (quad == 0) {
        #pragma unroll
        for (int qi = 0; qi < 4; qi++)
            pL[(size_t)z * BH_ * T_ + (size_t)bh * T_ + q0 + w * 64 + qi * 16 + r]
                = lacc[qi][0];
    }
}

// ---------------- combine: AO = (O0+O1)/(l0+l1), bf16 -----------------------
__global__ __launch_bounds__(256) void combine_kernel(
    const float* __restrict__ pO, const float* __restrict__ pL, u16* __restrict__ AO)
{
    const size_t SP = (size_t)BH_ * T_ * DK_;
    int bh = blockIdx.y;
    int b = bh / H_, h = bh % H_;
    int q = blockIdx.x * 64 + (threadIdx.x >> 2);
    int dk0 = (threadIdx.x & 3) * 16;
    size_t idx = ((size_t)bh * T_ + q) * DK_ + dk0;
    float l0 = pL[(size_t)bh * T_ + q];
    float l1 = pL[(size_t)BH_ * T_ + (size_t)bh * T_ + q];
    float inv = 1.0f / (l0 + l1);
    u16* dst = AO + ((size_t)b * T_ + q) * D_ + h * DK_ + dk0;
    #pragma unroll
    for (int i = 0; i < 2; i++) {
        float4 a0 = *(const float4*)&pO[idx + i * 8];
        float4 a1 = *(const float4*)&pO[idx + i * 8 + 4];
        float4 b0 = *(const float4*)&pO[SP + idx + i * 8];
        float4 b1 = *(const float4*)&pO[SP + idx + i * 8 + 4];
        uint4 dd;
        dd.x = pack2bf((a0.x + b0.x) * inv, (a0.y + b0.y) * inv);
        dd.y = pack2bf((a0.z + b0.z) * inv, (a0.w + b0.w) * inv);
        dd.z = pack2bf((a1.x + b1.x) * inv, (a1.y + b1.y) * inv);
        dd.w = pack2bf((a1.z + b1.z) * inv, (a1.w + b1.w) * inv);
        *(uint4*)&dst[i * 8] = dd;
    }
}

// ---------------- launch -----------------------------------------------------
extern "C" void kernel_launch(void* const* d_in, const int* in_sizes, int n_in,
                              void* d_out, int out_size, void* d_ws, size_t ws_size,
                              hipStream_t stream)
{
    const float* x  = (const float*)d_in[0];
    const float* wq = (const float*)d_in[1];
    const float* wk = (const float*)d_in[2];
    const float* wv = (const float*)d_in[3];
    const float* wp = (const float*)d_in[4];

    u16* ws = (u16*)d_ws;
    const size_t XS = (size_t)B_ * T_ * D_;
    const size_t WT = (size_t)D_ * D_;
    const size_t HS = (size_t)B_ * H_ * T_ * DK_;
    u16* xb = ws;                    // x as bf16
    u16* wt = xb + XS;               // 4 transposed weights
    u16* q  = wt + 4 * WT;           // Q, K, VT each HS
    u16* k  = q + HS;
    u16* vt = k + HS;
    u16* ao = vt + HS;               // attention out bf16 [B*T][D]
    float* pL = (float*)(ao + HS);               // 2 * BH * T floats
    float* pO = pL + 2 * (size_t)BH_ * T_;       // 2 * BH * T * DK floats

    convert_x_kernel<<<dim3(3072), 256, 0, stream>>>(x, xb);
    wtrans_kernel<<<dim3(24, 24, 4), dim3(32, 8), 0, stream>>>(wq, wk, wv, wp, wt);
    gemm_bt<0><<<dim3(18, 64), 256, 0, stream>>>(xb, wt, q);
    attn_kernel<<<dim3(768), 256, 0, stream>>>(q, k, vt, pO, pL);
    combine_kernel<<<dim3(64, 24), 256, 0, stream>>>(pO, pL, ao);
    gemm_bt<1><<<dim3(6, 64), 256, 0, stream>>>(ao, wt + 3 * WT, d_out);
}